// Round 1
// baseline (189.775 us; speedup 1.0000x reference)
//
#include <hip/hip_runtime.h>

// Wide (wide-and-deep "wide" tower) fused kernel:
//   out[b] = dot(dense[b,:13], dense_w)
//          + sum_i emb_table[i, idx[b,i]]            (26 dim-1 gathers)
//          + cross0[idx[b,0]*5000 + idx[b,1]]
//          + cross1[idx[b,2]*5000 + idx[b,3]]
//
// One thread per row. Total traffic ~20 MB -> latency bound, not BW bound.

constexpr int N_DENSE  = 13;
constexpr int N_SPARSE = 26;
constexpr int VOCAB    = 5000;

__global__ __launch_bounds__(256) void wide_fused_kernel(
    const float* __restrict__ dense,       // [B, 13]
    const float* __restrict__ emb_table,   // [26, 5000]
    const float* __restrict__ cross0,      // [25e6]
    const float* __restrict__ cross1,      // [25e6]
    const float* __restrict__ dense_w,     // [13]
    const int*   __restrict__ sparse_idx,  // [B, 26] (int32)
    float*       __restrict__ out,         // [B]
    int B)
{
    int b = blockIdx.x * blockDim.x + threadIdx.x;
    if (b >= B) return;

    const int* ir = sparse_idx + (size_t)b * N_SPARSE;

    // Read the 4 cross-feature indices first and issue the two long-latency
    // random gathers as early as possible (independent of everything else).
    int v0 = ir[0];
    int v1 = ir[1];
    int v2 = ir[2];
    int v3 = ir[3];
    float cr0 = cross0[v0 * VOCAB + v1];   // < 2^31, int32 math safe
    float cr1 = cross1[v2 * VOCAB + v3];

    // Dense dot product (dense_w is wave-uniform -> scalar-cached).
    float acc = 0.f;
    const float* dr = dense + (size_t)b * N_DENSE;
    #pragma unroll
    for (int j = 0; j < N_DENSE; ++j) acc += dr[j] * dense_w[j];

    // 26 dim-1 embedding gathers; emb_table is 520 KB -> L2/L3 resident.
    acc += emb_table[0 * VOCAB + v0];
    acc += emb_table[1 * VOCAB + v1];
    acc += emb_table[2 * VOCAB + v2];
    acc += emb_table[3 * VOCAB + v3];
    #pragma unroll
    for (int i = 4; i < N_SPARSE; ++i) {
        acc += emb_table[i * VOCAB + ir[i]];
    }

    out[b] = acc + cr0 + cr1;
}

extern "C" void kernel_launch(void* const* d_in, const int* in_sizes, int n_in,
                              void* d_out, int out_size, void* d_ws, size_t ws_size,
                              hipStream_t stream) {
    const float* dense   = (const float*)d_in[0];
    const float* emb     = (const float*)d_in[1];
    const float* cross0  = (const float*)d_in[2];
    const float* cross1  = (const float*)d_in[3];
    const float* dense_w = (const float*)d_in[4];
    const int*   idx     = (const int*)d_in[5];
    float* out = (float*)d_out;

    int B = out_size;                      // [B,1] output, B elements
    const int block = 256;
    const int grid  = (B + block - 1) / block;
    wide_fused_kernel<<<grid, block, 0, stream>>>(
        dense, emb, cross0, cross1, dense_w, idx, out, B);
}